// Round 1
// baseline (482.246 us; speedup 1.0000x reference)
//
#include <hip/hip_runtime.h>
#include <hip/hip_bf16.h>

#define N_IMG 1024
#define N_VIEWS 90
#define CENTER 512

// Radon transform: out[X, a] = sum_Y bilinear(img, y_in(X,Y,a), x_in(X,Y,a))
//   x_in =  ca*X + sa*Y - CENTER*(ca+sa-1)
//   y_in = -sa*X + ca*Y - CENTER*(ca-sa-1)
// Block: 256 threads = 4 waves. blockIdx.x = X-tile (64 cols), blockIdx.y = angle.
// Wave w handles Y in [w*256, w*256+256); lanes are consecutive X for locality.
__global__ __launch_bounds__(256) void radon_kernel(const float* __restrict__ img,
                                                    const float* __restrict__ theta,
                                                    float* __restrict__ out) {
    const int a    = blockIdx.y;
    const int tid  = threadIdx.x;
    const int lane = tid & 63;
    const int wave = tid >> 6;                 // 0..3 -> Y chunk
    const int X    = blockIdx.x * 64 + lane;

    const float ang = theta[a] * 0.017453292519943295f;
    float sa, ca;
    __sincosf(ang, &sa, &ca);                  // fast sincos; tolerance is ~2.76 abs

    const float Xf  = (float)X;
    const float fx0 =  ca * Xf - (float)CENTER * (ca + sa - 1.0f);
    const float fy0 = -sa * Xf - (float)CENTER * (ca - sa - 1.0f);

    float acc = 0.0f;
    const int y_begin = wave * 256;

    #pragma unroll 4
    for (int i = 0; i < 256; ++i) {
        const float Yf   = (float)(y_begin + i);
        const float x_in = fmaf(sa, Yf, fx0);
        const float y_in = fmaf(ca, Yf, fy0);

        // Fully-outside skip: contribution provably zero.
        if (x_in <= -1.0f || x_in >= (float)N_IMG ||
            y_in <= -1.0f || y_in >= (float)N_IMG) continue;

        const float x0f = floorf(x_in);
        const float y0f = floorf(y_in);
        const float wx  = x_in - x0f;
        const float wy  = y_in - y0f;
        const int x0 = (int)x0f;
        const int y0 = (int)y0f;

        const int x0c = min(max(x0,     0), N_IMG - 1);
        const int x1c = min(max(x0 + 1, 0), N_IMG - 1);
        const int y0c = min(max(y0,     0), N_IMG - 1);
        const int y1c = min(max(y0 + 1, 0), N_IMG - 1);

        const float wxa = (x0     >= 0 && x0     < N_IMG) ? (1.0f - wx) : 0.0f;
        const float wxb = (x0 + 1 >= 0 && x0 + 1 < N_IMG) ? wx          : 0.0f;
        const float wya = (y0     >= 0 && y0     < N_IMG) ? (1.0f - wy) : 0.0f;
        const float wyb = (y0 + 1 >= 0 && y0 + 1 < N_IMG) ? wy          : 0.0f;

        const float* row0 = img + y0c * N_IMG;
        const float* row1 = img + y1c * N_IMG;
        const float v00 = row0[x0c];
        const float v01 = row0[x1c];
        const float v10 = row1[x0c];
        const float v11 = row1[x1c];

        acc += wya * fmaf(v00, wxa, v01 * wxb)
             + wyb * fmaf(v10, wxa, v11 * wxb);
    }

    __shared__ float partial[4][64];
    partial[wave][lane] = acc;
    __syncthreads();
    if (wave == 0) {
        const float s = partial[0][lane] + partial[1][lane]
                      + partial[2][lane] + partial[3][lane];
        out[X * N_VIEWS + a] = s;
    }
}

extern "C" void kernel_launch(void* const* d_in, const int* in_sizes, int n_in,
                              void* d_out, int out_size, void* d_ws, size_t ws_size,
                              hipStream_t stream) {
    const float* img   = (const float*)d_in[0];   // [1024, 1024] f32
    const float* theta = (const float*)d_in[1];   // [90] f32 degrees
    float* out = (float*)d_out;                   // [1024, 90] f32

    dim3 grid(N_IMG / 64, N_VIEWS);               // 16 x 90 = 1440 blocks
    radon_kernel<<<grid, 256, 0, stream>>>(img, theta, out);
}

// Round 2
// 205.060 us; speedup vs baseline: 2.3517x; 2.3517x over previous
//
#include <hip/hip_runtime.h>

#define N_IMG  1024
#define N_VIEWS 90
#define CENTER  512
#define TILE     64
// bbox: cols <= 63*sqrt(2)+2 (floor slack) + 3 (align-down) = 95; rows <= 92
#define MAXH     92
#define MAXSTRIDE 97
#define LDS_WORDS (MAXH * MAXSTRIDE)   // 8924 words = 35,696 B -> 4 blocks/CU

// x_in =  ca*X + sa*Y + cx,  cx = CENTER*(1 - ca - sa)
// y_in = -sa*X + ca*Y + cy,  cy = CENTER*(1 - ca + sa)
// Evaluated with a fixed fmaf chain so corner extremes == sample extremes (fma monotone).
__device__ __forceinline__ void map_coords(float ca, float sa, float cx, float cy,
                                           float Xf, float Yf,
                                           float& x_in, float& y_in) {
    const float fx0 = fmaf(ca, Xf, cx);
    const float fy0 = fmaf(-sa, Xf, cy);
    x_in = fmaf(sa, Yf, fx0);
    y_in = fmaf(ca, Yf, fy0);
}

__global__ __launch_bounds__(256) void radon_tile_kernel(const float* __restrict__ img,
                                                         const float* __restrict__ theta,
                                                         float* __restrict__ out) {
    const int a  = blockIdx.z;
    const int X0 = blockIdx.x * TILE;
    const int Y0 = blockIdx.y * TILE;
    const int tid  = threadIdx.x;
    const int lane = tid & 63;
    const int wv   = tid >> 6;

    const float ang = theta[a] * 0.017453292519943295f;
    float sa, ca;
    __sincosf(ang, &sa, &ca);
    const float cx = (float)CENTER * (1.0f - ca - sa);
    const float cy = (float)CENTER * (1.0f - ca + sa);

    // ---- bbox from the 4 tile corners (same fmaf chain as samples) ----
    float x00, y00, x01, y01, x10, y10, x11, y11;
    map_coords(ca, sa, cx, cy, (float)X0,            (float)Y0,            x00, y00);
    map_coords(ca, sa, cx, cy, (float)(X0 + 63),     (float)Y0,            x01, y01);
    map_coords(ca, sa, cx, cy, (float)X0,            (float)(Y0 + 63),     x10, y10);
    map_coords(ca, sa, cx, cy, (float)(X0 + 63),     (float)(Y0 + 63),     x11, y11);
    const float xmin = fminf(fminf(x00, x01), fminf(x10, x11));
    const float xmax = fmaxf(fmaxf(x00, x01), fmaxf(x10, x11));
    const float ymin = fminf(fminf(y00, y01), fminf(y10, y11));
    const float ymax = fmaxf(fmaxf(y00, y01), fmaxf(y10, y11));

    const int ix0_raw = (int)floorf(xmin);
    const int ix1_raw = (int)floorf(xmax) + 1;
    const int iy0_raw = (int)floorf(ymin);
    const int iy1_raw = (int)floorf(ymax) + 1;

    const int ix0 = max(0, ix0_raw);
    const int ix1 = min(N_IMG - 1, ix1_raw);
    const int iy0 = max(0, iy0_raw);
    const int iy1 = min(N_IMG - 1, iy1_raw);
    if (ix1 < ix0 || iy1 < iy0) return;   // whole tile maps outside image (out pre-zeroed)

    const int xstart = ix0 & ~3;          // float4-aligned global reads
    const int h = iy1 - iy0 + 1;          // <= 92
    // bank swizzle: stride 95 => bank ~ (x - y) % 32, lane step |ca+sa| >= 1 (theta < 90)
    //               stride 97 => bank ~ (x + y) % 32, lane step |ca-sa| >= 1 (theta >= 90)
    const int stride = (ca > 0.0f) ? 95 : 97;

    __shared__ float tile[LDS_WORDS];

    // ---- stage bbox rows into LDS (coalesced float4 global reads) ----
    const int items = h * 24;             // 24 float4-columns cover width <= 95
    for (int idx = tid; idx < items; idx += 256) {
        const int r  = idx / 24;
        const int c4 = idx - r * 24;
        const int gx = xstart + c4 * 4;
        if (gx > ix1) continue;
        const float* rowp = img + (iy0 + r) * N_IMG;
        float* dst = tile + r * stride + (gx - xstart);
        if (gx + 3 <= ix1) {
            const float4 v = *(const float4*)(rowp + gx);
            dst[0] = v.x; dst[1] = v.y; dst[2] = v.z; dst[3] = v.w;
        } else {
            for (int j = 0; j < 4 && gx + j <= ix1; ++j) dst[j] = rowp[gx + j];
        }
    }
    __syncthreads();

    // ---- per-sample bilinear from LDS ----
    const int X = X0 + lane;
    const float Xf  = (float)X;
    const float fx0 = fmaf(ca, Xf, cx);
    const float fy0 = fmaf(-sa, Xf, cy);
    const int Ybase = Y0 + wv * 16;
    float acc = 0.0f;

    const bool interior = (ix0_raw >= 0) && (ix1_raw <= N_IMG - 1) &&
                          (iy0_raw >= 0) && (iy1_raw <= N_IMG - 1);
    if (interior) {
        #pragma unroll
        for (int i = 0; i < 16; ++i) {
            const float Yf   = (float)(Ybase + i);
            const float x_in = fmaf(sa, Yf, fx0);
            const float y_in = fmaf(ca, Yf, fy0);
            const float x0f = floorf(x_in);
            const float y0f = floorf(y_in);
            const float wx  = x_in - x0f;
            const float wy  = y_in - y0f;
            const int li = ((int)y0f - iy0) * stride + ((int)x0f - xstart);
            const float t00 = tile[li];
            const float t01 = tile[li + 1];
            const float t10 = tile[li + stride];
            const float t11 = tile[li + stride + 1];
            const float top = fmaf(wx, t01 - t00, t00);
            const float bot = fmaf(wx, t11 - t10, t10);
            acc += fmaf(wy, bot - top, top);
        }
    } else {
        #pragma unroll
        for (int i = 0; i < 16; ++i) {
            const float Yf   = (float)(Ybase + i);
            const float x_in = fmaf(sa, Yf, fx0);
            const float y_in = fmaf(ca, Yf, fy0);
            const float x0f = floorf(x_in);
            const float y0f = floorf(y_in);
            const float wx  = x_in - x0f;
            const float wy  = y_in - y0f;
            const int x0 = (int)x0f;
            const int y0 = (int)y0f;
            const int x0c = min(max(x0,     0), N_IMG - 1);
            const int x1c = min(max(x0 + 1, 0), N_IMG - 1);
            const int y0c = min(max(y0,     0), N_IMG - 1);
            const int y1c = min(max(y0 + 1, 0), N_IMG - 1);
            const float wxa = (x0     >= 0 && x0     < N_IMG) ? (1.0f - wx) : 0.0f;
            const float wxb = (x0 + 1 >= 0 && x0 + 1 < N_IMG) ? wx          : 0.0f;
            const float wya = (y0     >= 0 && y0     < N_IMG) ? (1.0f - wy) : 0.0f;
            const float wyb = (y0 + 1 >= 0 && y0 + 1 < N_IMG) ? wy          : 0.0f;
            const int r0 = (y0c - iy0) * stride;
            const int r1 = (y1c - iy0) * stride;
            const float t00 = tile[r0 + (x0c - xstart)];
            const float t01 = tile[r0 + (x1c - xstart)];
            const float t10 = tile[r1 + (x0c - xstart)];
            const float t11 = tile[r1 + (x1c - xstart)];
            acc += wya * fmaf(wxa, t00, wxb * t01)
                 + wyb * fmaf(wxa, t10, wxb * t11);
        }
    }

    // ---- block reduce (4 waves per X column) + one atomic per X ----
    __syncthreads();
    tile[wv * 64 + lane] = acc;
    __syncthreads();
    if (wv == 0) {
        const float s = tile[lane] + tile[64 + lane] + tile[128 + lane] + tile[192 + lane];
        atomicAdd(&out[X * N_VIEWS + a], s);
    }
}

extern "C" void kernel_launch(void* const* d_in, const int* in_sizes, int n_in,
                              void* d_out, int out_size, void* d_ws, size_t ws_size,
                              hipStream_t stream) {
    const float* img   = (const float*)d_in[0];   // [1024, 1024] f32
    const float* theta = (const float*)d_in[1];   // [90] f32 degrees
    float* out = (float*)d_out;                   // [1024, 90] f32

    hipMemsetAsync(d_out, 0, (size_t)out_size * sizeof(float), stream);
    dim3 grid(N_IMG / TILE, N_IMG / TILE, N_VIEWS);   // 16 x 16 x 90
    radon_tile_kernel<<<grid, 256, 0, stream>>>(img, theta, out);
}